// Round 14
// baseline (496.615 us; speedup 1.0000x reference)
//
#include <hip/hip_runtime.h>

#define T_SEQ 512
#define HID 64
#define MB 16             // batch rows per block
#define NTHREADS 512      // 8 waves, each: 2 L1 tiles + 2 L2 tiles (merged roles)
// OPERAND-FLIPPED MFMA: A = weights (regs), B = h (LDS). D[gate-unit][batch].
// MERGED ROLES: wave w owns units w*8..w*8+7 for BOTH layers; h1 read-set
// {hf0,hf1} feeds both L1 and L2 -> 5 b128/wave, 40/CU-iter (R13-validated via
// conflict counter 3.36e7->2.52e7). R13 failed on REGISTERS, not LDS: backend
// heuristic spilled to chase 8 waves/EU. Fix: amdgpu_waves_per_eu(4,4) pins
// 4 waves/EU -> 128-VGPR budget, no spill incentive. 2 blocks/CU.
#define A1STR 104   // shorts; 52 dw == 20 mod 32 -> full bank spread, 2-way max
#define A2STR 104

typedef __attribute__((ext_vector_type(8))) short short8;
typedef __attribute__((ext_vector_type(4))) float floatx4;

#define LOG2E 1.4426950408889634f

__device__ __forceinline__ short f2bf_rne(float v) {
  unsigned u = __float_as_uint(v);
  return (short)((u + 0x7FFFu + ((u >> 16) & 1u)) >> 16);
}
__device__ __forceinline__ float rcp_(float x) { return __builtin_amdgcn_rcpf(x); }
__device__ __forceinline__ float exp2_(float x) { return __builtin_amdgcn_exp2f(x); }

// gates pre-scaled: p[0,1,3] by LOG2E, p[2] by 2*LOG2E. rcp-fused:
// sig(i)*tanh(g) = (G-1)*rcp((1+A)(G+1)); h = (C-1)*rcp((1+O)(C+1))
__device__ __forceinline__ float gate_h(const floatx4 p, float& c) {
  float A = exp2_(-p[0]);
  float F = exp2_(-p[1]);
  float G = exp2_(p[2]);
  float O = exp2_(-p[3]);
  float ig = (G - 1.f) * rcp_((1.f + A) * (G + 1.f));
  c = rcp_(1.f + F) * c + ig;
  float C = exp2_((2.f * LOG2E) * c);
  return (C - 1.f) * rcp_((1.f + O) * (C + 1.f));
}

// unit stored at LDS h-position p
__device__ __forceinline__ int uofp(int p) {
  return (p & ~7) + ((p & 7) >> 1) + ((p & 1) << 2);
}

// Layer-1 weight at A-frag k-slot (K1=96): k<64 pairs h1 positions, 64..70 x
__device__ __forceinline__ short w1elem(int k, int n, float wsc,
                                        const float* __restrict__ Wih0,
                                        const float* __restrict__ Whh0) {
  float v;
  if      (k < 64) { v = Whh0[n*64 + uofp(k)]; }
  else if (k < 71) { v = Wih0[n*7 + (k - 64)]; }
  else return (short)0;
  return f2bf_rne(v * wsc);
}
// Layer-2 weight (K2=128): k<64 pairs h1 positions, 64..127 pairs h2 positions
__device__ __forceinline__ short w2elem(int k, int n, float wsc,
                                        const float* __restrict__ Wih1,
                                        const float* __restrict__ Whh1) {
  float v;
  if (k < 64) { v = Wih1[n*64 + uofp(k)]; }
  else        { v = Whh1[n*64 + uofp(k - 64)]; }
  return f2bf_rne(v * wsc);
}

// A = weights (first arg), B = h (second arg)
#define MFMA(A, B, C) __builtin_amdgcn_mfma_f32_16x16x32_bf16((A), (B), (C), 0, 0, 0)

#define PACK2(ha, hb)                                                        \
  ((unsigned)(unsigned short)f2bf_rne(ha) |                                  \
   ((unsigned)(unsigned short)f2bf_rne(hb) << 16))

__global__ __launch_bounds__(NTHREADS)
__attribute__((amdgpu_waves_per_eu(4, 4)))
void lstm_fused(
    const float* __restrict__ x,
    const float* __restrict__ Wih0, const float* __restrict__ Whh0,
    const float* __restrict__ bih0, const float* __restrict__ bhh0,
    const float* __restrict__ Wih1, const float* __restrict__ Whh1,
    const float* __restrict__ bih1, const float* __restrict__ bhh1,
    const float* __restrict__ Wfc,  const float* __restrict__ bfc,
    float* __restrict__ out)
{
  __shared__ __align__(16) short A1[2][MB][A1STR];
  __shared__ __align__(16) short A2[2][MB][A2STR];
  __shared__ float h2f[MB][HID + 4];

  const int tid  = threadIdx.x;
  const int lane = tid & 63;
  const int wave = tid >> 6;           // 0..7
  const int l15  = lane & 15;          // batch column
  const int quad = lane >> 4;
  const int quad8= quad * 8;
  const int g4   = l15 & 3;
  const int b0   = blockIdx.x * MB;
  const int u0   = wave*8 + quad;      // tile-a owned unit (both layers)
  const int u1   = u0 + 4;             // tile-b owned unit
  const int hpos = wave*8 + 2*quad;    // packed h position (shorts, even)
  const int n0   = g4*64 + (wave*8 + (l15 >> 2));  // tile-a weight row
  const int n1   = n0 + 4;                         // tile-b weight row
  const float wsc = (g4 == 2) ? 2.f * LOG2E : LOG2E;

  // ---- zero both staging buffers (h(-1) = 0, x pad = 0) ----
  for (int i = tid; i < 2*MB*A1STR/2; i += NTHREADS) ((unsigned*)A1)[i] = 0u;
  for (int i = tid; i < 2*MB*A2STR/2; i += NTHREADS) ((unsigned*)A2)[i] = 0u;

  // ---- biases for owned units, both layers ----
  floatx4 b1a, b1b, b2a, b2b;
  #pragma unroll
  for (int g = 0; g < 4; ++g) {
    float ws = (g == 2) ? 2.f * LOG2E : LOG2E;
    b1a[g] = (bih0[g*64 + u0] + bhh0[g*64 + u0]) * ws;
    b1b[g] = (bih0[g*64 + u1] + bhh0[g*64 + u1]) * ws;
    b2a[g] = (bih1[g*64 + u0] + bhh1[g*64 + u0]) * ws;
    b2b[g] = (bih1[g*64 + u1] + bhh1[g*64 + u1]) * ws;
  }

  // ---- x staging: each wave stages rows 2w, 2w+1 ----
  const int xd   = lane & 31;
  const int xrow = 2*wave + (lane >> 5);
  const bool xact = (xd < 7);
  const float* xbase = x + ((size_t)(b0 + xrow) * T_SEQ) * 7 + xd;
  float xcur = 0.f;
  if (xact) {
    A1[0][xrow][64 + xd] = f2bf_rne(xbase[0]);
    xcur = xbase[7];
  }

  // ---- weight A-fragments: L1 [3 ksteps][2 tiles], L2 [4][2] ----
  short8 W1f[3][2], W2f[4][2];
  #pragma unroll
  for (int ks = 0; ks < 3; ++ks) {
    short8 fa, fb;
    #pragma unroll
    for (int jj = 0; jj < 8; ++jj) {
      fa[jj] = w1elem(ks*32 + quad8 + jj, n0, wsc, Wih0, Whh0);
      fb[jj] = w1elem(ks*32 + quad8 + jj, n1, wsc, Wih0, Whh0);
    }
    W1f[ks][0] = fa; W1f[ks][1] = fb;
  }
  #pragma unroll
  for (int ks = 0; ks < 4; ++ks) {
    short8 fa, fb;
    #pragma unroll
    for (int jj = 0; jj < 8; ++jj) {
      fa[jj] = w2elem(ks*32 + quad8 + jj, n0, wsc, Wih1, Whh1);
      fb[jj] = w2elem(ks*32 + quad8 + jj, n1, wsc, Wih1, Whh1);
    }
    W2f[ks][0] = fa; W2f[ks][1] = fb;
  }
  __syncthreads();

  float c1a = 0.f, c1b = 0.f, c2a = 0.f, c2b = 0.f;

#define STEP_X(NXT, XT)                                                      \
    if (xact) {                                                              \
      A1[NXT][xrow][64 + xd] = f2bf_rne(xcur);                               \
      xcur = xbase[7 * (XT)];                                                \
    }

#define STEP_FULL(CUR, NXT, IT)                                              \
  {                                                                          \
    int xt_ = (IT) + 2; if (xt_ > T_SEQ - 1) xt_ = T_SEQ - 1;                \
    STEP_X(NXT, xt_)                                                         \
    short8 hf0 = *(const short8*)&A1[CUR][l15][     quad8];                  \
    short8 hf1 = *(const short8*)&A1[CUR][l15][32 + quad8];                  \
    short8 hfx = *(const short8*)&A1[CUR][l15][64 + quad8];                  \
    short8 h20 = *(const short8*)&A2[CUR][l15][     quad8];                  \
    short8 h21 = *(const short8*)&A2[CUR][l15][32 + quad8];                  \
    floatx4 pa = b1a, pb = b1b, qa = b2a, qb = b2b;                          \
    pa = MFMA(W1f[0][0], hf0, pa);  pb = MFMA(W1f[0][1], hf0, pb);           \
    qa = MFMA(W2f[0][0], hf0, qa);  qb = MFMA(W2f[0][1], hf0, qb);           \
    pa = MFMA(W1f[1][0], hf1, pa);  pb = MFMA(W1f[1][1], hf1, pb);           \
    qa = MFMA(W2f[1][0], hf1, qa);  qb = MFMA(W2f[1][1], hf1, qb);           \
    pa = MFMA(W1f[2][0], hfx, pa);  pb = MFMA(W1f[2][1], hfx, pb);           \
    qa = MFMA(W2f[2][0], h20, qa);  qb = MFMA(W2f[2][1], h20, qb);           \
    qa = MFMA(W2f[3][0], h21, qa);  qb = MFMA(W2f[3][1], h21, qb);           \
    {                                                                        \
      float ha = gate_h(pa, c1a);                                            \
      float hb = gate_h(pb, c1b);                                            \
      *(unsigned*)&A1[NXT][l15][hpos] = PACK2(ha, hb);                       \
    }                                                                        \
    {                                                                        \
      float ha = gate_h(qa, c2a);                                            \
      float hb = gate_h(qb, c2b);                                            \
      *(unsigned*)&A2[NXT][l15][hpos] = PACK2(ha, hb);                       \
    }                                                                        \
    __syncthreads();                                                         \
  }

  // ---- it = 0: L1 + x only (A2[1] keeps zeros = h2(-1)) ----
  {
    STEP_X(1, 2)
    short8 hf0 = *(const short8*)&A1[0][l15][     quad8];
    short8 hf1 = *(const short8*)&A1[0][l15][32 + quad8];
    short8 hfx = *(const short8*)&A1[0][l15][64 + quad8];
    floatx4 pa = b1a, pb = b1b;
    pa = MFMA(W1f[0][0], hf0, pa);  pb = MFMA(W1f[0][1], hf0, pb);
    pa = MFMA(W1f[1][0], hf1, pa);  pb = MFMA(W1f[1][1], hf1, pb);
    pa = MFMA(W1f[2][0], hfx, pa);  pb = MFMA(W1f[2][1], hfx, pb);
    float ha = gate_h(pa, c1a);
    float hb = gate_h(pb, c1b);
    *(unsigned*)&A1[1][l15][hpos] = PACK2(ha, hb);
    __syncthreads();
  }

  // ---- main: it = 1..510, two steps per trip ----
  #pragma unroll 1
  for (int k = 0; k < 255; ++k) {
    STEP_FULL(1, 0, 2*k + 1)
    STEP_FULL(0, 1, 2*k + 2)
  }
  // ---- it = 511 ----
  STEP_FULL(1, 0, 511)

  // ---- it = 512: L2 only; write final h2 as f32 (natural unit index) ----
  {
    short8 hf0 = *(const short8*)&A1[0][l15][     quad8];
    short8 hf1 = *(const short8*)&A1[0][l15][32 + quad8];
    short8 h20 = *(const short8*)&A2[0][l15][     quad8];
    short8 h21 = *(const short8*)&A2[0][l15][32 + quad8];
    floatx4 qa = b2a, qb = b2b;
    qa = MFMA(W2f[0][0], hf0, qa);  qb = MFMA(W2f[0][1], hf0, qb);
    qa = MFMA(W2f[1][0], hf1, qa);  qb = MFMA(W2f[1][1], hf1, qb);
    qa = MFMA(W2f[2][0], h20, qa);  qb = MFMA(W2f[2][1], h20, qb);
    qa = MFMA(W2f[3][0], h21, qa);  qb = MFMA(W2f[3][1], h21, qb);
    h2f[l15][u0] = gate_h(qa, c2a);
    h2f[l15][u1] = gate_h(qb, c2b);
    __syncthreads();
  }

  // ---- final FC ----
  if (tid < MB * 4) {
    int bbf = tid >> 2, o = tid & 3;
    float acc = bfc[o];
    #pragma unroll 8
    for (int kk = 0; kk < HID; ++kk) acc += h2f[bbf][kk] * Wfc[o*HID + kk];
    out[(size_t)(b0 + bbf) * 4 + o] = acc;
  }
}

extern "C" void kernel_launch(void* const* d_in, const int* in_sizes, int n_in,
                              void* d_out, int out_size, void* d_ws, size_t ws_size,
                              hipStream_t stream) {
  const float* x    = (const float*)d_in[0];
  const float* Wih0 = (const float*)d_in[1];
  const float* Whh0 = (const float*)d_in[2];
  const float* bih0 = (const float*)d_in[3];
  const float* bhh0 = (const float*)d_in[4];
  const float* Wih1 = (const float*)d_in[5];
  const float* Whh1 = (const float*)d_in[6];
  const float* bih1 = (const float*)d_in[7];
  const float* bhh1 = (const float*)d_in[8];
  const float* Wfc  = (const float*)d_in[9];
  const float* bfc  = (const float*)d_in[10];
  (void)d_ws; (void)ws_size; (void)n_in; (void)out_size;

  const int B = in_sizes[0] / (T_SEQ * 7);   // 4096
  dim3 grid(B / MB);
  lstm_fused<<<grid, NTHREADS, 0, stream>>>(x, Wih0, Whh0, bih0, bhh0,
                                            Wih1, Whh1, bih1, bhh1, Wfc, bfc,
                                            (float*)d_out);
}

// Round 15
// 445.790 us; speedup vs baseline: 1.1140x; 1.1140x over previous
//
#include <hip/hip_runtime.h>

#define T_SEQ 512
#define HID 64
#define MB 16             // batch rows per block
#define NTHREADS 1024     // 16 waves: 0-7 layer1 (2 tiles), 8-15 layer2 (2 tiles)
// OPERAND-FLIPPED MFMA: A = weights (regs), B = h (LDS). D[gate-unit][batch].
// LAYER-SPLIT: L1 waves read {h1 x2, x} = 3 b128; L2 waves read {h1 x2, h2 x2}
// = 4 -> 56 b128/CU-iter, which is the floor for this decomposition:
// ceil(71/32)*8 + ceil(128/32)*8, every h crosses waves via LDS.
// UNIT PERMUTATION: position p holds unit uofp(p) -> packed b32 h-stores.
// Strides 104 shorts = 52 dw == 20 mod 32 -> 2-way max bank aliasing.
// R11/R13/R14 lessons: >2 tiles/wave spills (allocator caps 64 VGPR; both
// __launch_bounds__ min-waves and amdgpu_waves_per_eu failed to lift it);
// 512-thread blocks halve waves/CU (grid fixed at 256 = B/MB).
#define A1STR 104
#define A2STR 104

typedef __attribute__((ext_vector_type(8))) short short8;
typedef __attribute__((ext_vector_type(4))) float floatx4;

#define LOG2E 1.4426950408889634f

__device__ __forceinline__ short f2bf_rne(float v) {
  unsigned u = __float_as_uint(v);
  return (short)((u + 0x7FFFu + ((u >> 16) & 1u)) >> 16);
}
__device__ __forceinline__ float rcp_(float x) { return __builtin_amdgcn_rcpf(x); }
__device__ __forceinline__ float exp2_(float x) { return __builtin_amdgcn_exp2f(x); }

// gates pre-scaled: p[0,1,3] by LOG2E, p[2] by 2*LOG2E. rcp-fused:
// sig(i)*tanh(g) = (G-1)*rcp((1+A)(G+1)); h = (C-1)*rcp((1+O)(C+1))
__device__ __forceinline__ float gate_h(const floatx4 p, float& c) {
  float A = exp2_(-p[0]);
  float F = exp2_(-p[1]);
  float G = exp2_(p[2]);
  float O = exp2_(-p[3]);
  float ig = (G - 1.f) * rcp_((1.f + A) * (G + 1.f));
  c = rcp_(1.f + F) * c + ig;
  float C = exp2_((2.f * LOG2E) * c);
  return (C - 1.f) * rcp_((1.f + O) * (C + 1.f));
}

// unit stored at LDS h-position p
__device__ __forceinline__ int uofp(int p) {
  return (p & ~7) + ((p & 7) >> 1) + ((p & 1) << 2);
}

// Layer-1 weight at A-frag k-slot (K1=96): k<64 pairs h1 positions, 64..70 x
__device__ __forceinline__ short w1elem(int k, int n, float wsc,
                                        const float* __restrict__ Wih0,
                                        const float* __restrict__ Whh0) {
  float v;
  if      (k < 64) { v = Whh0[n*64 + uofp(k)]; }
  else if (k < 71) { v = Wih0[n*7 + (k - 64)]; }
  else return (short)0;
  return f2bf_rne(v * wsc);
}
// Layer-2 weight (K2=128): k<64 pairs h1 positions, 64..127 pairs h2 positions
__device__ __forceinline__ short w2elem(int k, int n, float wsc,
                                        const float* __restrict__ Wih1,
                                        const float* __restrict__ Whh1) {
  float v;
  if (k < 64) { v = Wih1[n*64 + uofp(k)]; }
  else        { v = Whh1[n*64 + uofp(k - 64)]; }
  return f2bf_rne(v * wsc);
}

// A = weights (first arg), B = h (second arg)
#define MFMA(A, B, C) __builtin_amdgcn_mfma_f32_16x16x32_bf16((A), (B), (C), 0, 0, 0)

#define PACK2(ha, hb)                                                        \
  ((unsigned)(unsigned short)f2bf_rne(ha) |                                  \
   ((unsigned)(unsigned short)f2bf_rne(hb) << 16))

__global__ __launch_bounds__(NTHREADS, 4) void lstm_fused(
    const float* __restrict__ x,
    const float* __restrict__ Wih0, const float* __restrict__ Whh0,
    const float* __restrict__ bih0, const float* __restrict__ bhh0,
    const float* __restrict__ Wih1, const float* __restrict__ Whh1,
    const float* __restrict__ bih1, const float* __restrict__ bhh1,
    const float* __restrict__ Wfc,  const float* __restrict__ bfc,
    float* __restrict__ out)
{
  __shared__ __align__(16) short A1[2][MB][A1STR];
  __shared__ __align__(16) short A2[2][MB][A2STR];
  __shared__ float h2f[MB][HID + 4];

  const int tid  = threadIdx.x;
  const int lane = tid & 63;
  const int wave = tid >> 6;           // 0..15
  const int wl   = wave & 7;           // index within layer group
  const bool isL1 = wave < 8;
  const int l15  = lane & 15;          // batch column
  const int quad = lane >> 4;
  const int quad8= quad * 8;
  const int g4   = l15 & 3;
  const int b0   = blockIdx.x * MB;
  const int u0   = wl*8 + quad;        // tile-0 owned unit
  const int u1   = u0 + 4;             // tile-1 owned unit
  const int hpos = wl*8 + 2*quad;      // packed h position (shorts, even)
  const int n0   = g4*64 + (wl*8 + (l15 >> 2));   // tile-0 weight row
  const int n1   = n0 + 4;                        // tile-1 weight row
  const float wsc = (g4 == 2) ? 2.f * LOG2E : LOG2E;

  // ---- zero both staging buffers (h(-1) = 0, x pad = 0) ----
  for (int i = tid; i < 2*MB*A1STR/2; i += NTHREADS) ((unsigned*)A1)[i] = 0u;
  for (int i = tid; i < 2*MB*A2STR/2; i += NTHREADS) ((unsigned*)A2)[i] = 0u;

  // ---- biases for owned units (this thread's layer) ----
  const float* bi_ = isL1 ? bih0 : bih1;
  const float* bh_ = isL1 ? bhh0 : bhh1;
  floatx4 bia, bib;
  #pragma unroll
  for (int g = 0; g < 4; ++g) {
    float ws = (g == 2) ? 2.f * LOG2E : LOG2E;
    bia[g] = (bi_[g*64 + u0] + bh_[g*64 + u0]) * ws;
    bib[g] = (bi_[g*64 + u1] + bh_[g*64 + u1]) * ws;
  }

  // ---- x staging: spread across all 8 L1 waves (2 batch rows each) ----
  const int xd   = lane & 31;
  const int xrow = 2*wl + (lane >> 5);
  const bool xact = isL1 && (xd < 7);
  const float* xbase = x + ((size_t)(b0 + xrow) * T_SEQ) * 7 + xd;
  const float* xlast = xbase + 7 * (T_SEQ - 1);   // clamp pointer (no OOB)
  const float* xp    = xbase + 7 * 2;             // -> x(2) after init loads
  float xcur = 0.f;
  if (xact) {
    A1[0][xrow][64 + xd] = f2bf_rne(xbase[0]);
    xcur = xbase[7];
  }

  // ---- weight A-fragments (per layer group; tiles a/b) ----
  short8 WA[4], WB[4];
  if (isL1) {
    #pragma unroll
    for (int ks = 0; ks < 3; ++ks) {
      short8 fa, fb;
      #pragma unroll
      for (int jj = 0; jj < 8; ++jj) {
        fa[jj] = w1elem(ks*32 + quad8 + jj, n0, wsc, Wih0, Whh0);
        fb[jj] = w1elem(ks*32 + quad8 + jj, n1, wsc, Wih0, Whh0);
      }
      WA[ks] = fa; WB[ks] = fb;
    }
  } else {
    #pragma unroll
    for (int ks = 0; ks < 4; ++ks) {
      short8 fa, fb;
      #pragma unroll
      for (int jj = 0; jj < 8; ++jj) {
        fa[jj] = w2elem(ks*32 + quad8 + jj, n0, wsc, Wih1, Whh1);
        fb[jj] = w2elem(ks*32 + quad8 + jj, n1, wsc, Wih1, Whh1);
      }
      WA[ks] = fa; WB[ks] = fb;
    }
  }
  __syncthreads();

  float ca = 0.f, cb = 0.f;   // c-state for owned (layer, unit) pair

// x: store x(it+1)=xcur into NXT, advance running pointer (clamped, no mul)
#define STEP_X(NXT)                                                          \
    if (xact) {                                                              \
      A1[NXT][xrow][64 + xd] = f2bf_rne(xcur);                               \
      xcur = *xp;                                                            \
      xp = (xp < xlast) ? xp + 7 : xlast;                                    \
    }

#define STEP_FULL(CUR, NXT)                                                  \
  {                                                                          \
    if (isL1) {                                                              \
      STEP_X(NXT)                                                            \
      short8 hf0 = *(const short8*)&A1[CUR][l15][     quad8];                \
      short8 hf1 = *(const short8*)&A1[CUR][l15][32 + quad8];                \
      short8 hfx = *(const short8*)&A1[CUR][l15][64 + quad8];                \
      floatx4 pa = bia, pb = bib;                                            \
      pa = MFMA(WA[0], hf0, pa);  pb = MFMA(WB[0], hf0, pb);                 \
      pa = MFMA(WA[1], hf1, pa);  pb = MFMA(WB[1], hf1, pb);                 \
      pa = MFMA(WA[2], hfx, pa);  pb = MFMA(WB[2], hfx, pb);                 \
      float ha = gate_h(pa, ca);                                             \
      float hb = gate_h(pb, cb);                                             \
      *(unsigned*)&A1[NXT][l15][hpos] = PACK2(ha, hb);                       \
    } else {                                                                 \
      short8 h20 = *(const short8*)&A2[CUR][l15][     quad8];                \
      short8 h21 = *(const short8*)&A2[CUR][l15][32 + quad8];                \
      short8 hf0 = *(const short8*)&A1[CUR][l15][     quad8];                \
      short8 hf1 = *(const short8*)&A1[CUR][l15][32 + quad8];                \
      floatx4 pa = bia, pb = bib;                                            \
      pa = MFMA(WA[2], h20, pa);  pb = MFMA(WB[2], h20, pb);                 \
      pa = MFMA(WA[3], h21, pa);  pb = MFMA(WB[3], h21, pb);                 \
      pa = MFMA(WA[0], hf0, pa);  pb = MFMA(WB[0], hf0, pb);                 \
      pa = MFMA(WA[1], hf1, pa);  pb = MFMA(WB[1], hf1, pb);                 \
      float ha = gate_h(pa, ca);                                             \
      float hb = gate_h(pb, cb);                                             \
      *(unsigned*)&A2[NXT][l15][hpos] = PACK2(ha, hb);                       \
    }                                                                        \
    __syncthreads();                                                         \
  }

  // ---- it = 0: L1 only (A2[1] keeps zeros = h2(-1)) ----
  {
    if (isL1) {
      STEP_X(1)
      short8 hf0 = *(const short8*)&A1[0][l15][     quad8];
      short8 hf1 = *(const short8*)&A1[0][l15][32 + quad8];
      short8 hfx = *(const short8*)&A1[0][l15][64 + quad8];
      floatx4 pa = bia, pb = bib;
      pa = MFMA(WA[0], hf0, pa);  pb = MFMA(WB[0], hf0, pb);
      pa = MFMA(WA[1], hf1, pa);  pb = MFMA(WB[1], hf1, pb);
      pa = MFMA(WA[2], hfx, pa);  pb = MFMA(WB[2], hfx, pb);
      float ha = gate_h(pa, ca);
      float hb = gate_h(pb, cb);
      *(unsigned*)&A1[1][l15][hpos] = PACK2(ha, hb);
    }
    __syncthreads();
  }

  // ---- main: it = 1..510, two steps per trip ----
  #pragma unroll 1
  for (int k = 0; k < 255; ++k) {
    STEP_FULL(1, 0)
    STEP_FULL(0, 1)
  }
  // ---- it = 511 ----
  STEP_FULL(1, 0)

  // ---- it = 512: L2 only; write final h2 as f32 (natural unit index) ----
  {
    if (!isL1) {
      short8 h20 = *(const short8*)&A2[0][l15][     quad8];
      short8 h21 = *(const short8*)&A2[0][l15][32 + quad8];
      short8 hf0 = *(const short8*)&A1[0][l15][     quad8];
      short8 hf1 = *(const short8*)&A1[0][l15][32 + quad8];
      floatx4 pa = bia, pb = bib;
      pa = MFMA(WA[2], h20, pa);  pb = MFMA(WB[2], h20, pb);
      pa = MFMA(WA[3], h21, pa);  pb = MFMA(WB[3], h21, pb);
      pa = MFMA(WA[0], hf0, pa);  pb = MFMA(WB[0], hf0, pb);
      pa = MFMA(WA[1], hf1, pa);  pb = MFMA(WB[1], hf1, pb);
      h2f[l15][u0] = gate_h(pa, ca);
      h2f[l15][u1] = gate_h(pb, cb);
    }
    __syncthreads();
  }

  // ---- final FC ----
  if (tid < MB * 4) {
    int bbf = tid >> 2, o = tid & 3;
    float acc = bfc[o];
    #pragma unroll 8
    for (int kk = 0; kk < HID; ++kk) acc += h2f[bbf][kk] * Wfc[o*HID + kk];
    out[(size_t)(b0 + bbf) * 4 + o] = acc;
  }
}

extern "C" void kernel_launch(void* const* d_in, const int* in_sizes, int n_in,
                              void* d_out, int out_size, void* d_ws, size_t ws_size,
                              hipStream_t stream) {
  const float* x    = (const float*)d_in[0];
  const float* Wih0 = (const float*)d_in[1];
  const float* Whh0 = (const float*)d_in[2];
  const float* bih0 = (const float*)d_in[3];
  const float* bhh0 = (const float*)d_in[4];
  const float* Wih1 = (const float*)d_in[5];
  const float* Whh1 = (const float*)d_in[6];
  const float* bih1 = (const float*)d_in[7];
  const float* bhh1 = (const float*)d_in[8];
  const float* Wfc  = (const float*)d_in[9];
  const float* bfc  = (const float*)d_in[10];
  (void)d_ws; (void)ws_size; (void)n_in; (void)out_size;

  const int B = in_sizes[0] / (T_SEQ * 7);   // 4096
  dim3 grid(B / MB);
  lstm_fused<<<grid, NTHREADS, 0, stream>>>(x, Wih0, Whh0, bih0, bhh0,
                                            Wih1, Whh1, bih1, bhh1, Wfc, bfc,
                                            (float*)d_out);
}